// Round 4
// baseline (404.580 us; speedup 1.0000x reference)
//
#include <hip/hip_runtime.h>

#define LL 512
#define DD 128
#define HH 50
#define JW 520   // padded j' width (4 + 512 + 4)

typedef short v8s __attribute__((ext_vector_type(8)));
typedef float f32x4 __attribute__((ext_vector_type(4)));
typedef unsigned int u32x4 __attribute__((ext_vector_type(4)));

__device__ __forceinline__ unsigned cvtpk(float a, float b) {
  unsigned r;
  asm("v_cvt_pk_bf16_f32 %0, %1, %2" : "=v"(r) : "v"(a), "v"(b));
  return r;
}
__device__ __forceinline__ unsigned cvtpkabs(float a, float b) {
  unsigned r;
  asm("v_cvt_pk_bf16_f32 %0, abs(%1), abs(%2)" : "=v"(r) : "v"(a), "v"(b));
  return r;
}
__device__ __forceinline__ unsigned short f2bf(float f) {
  unsigned u = __builtin_bit_cast(unsigned, f);
  u = (u + 0x7fffu + ((u >> 16) & 1u)) >> 16;
  return (unsigned short)u;
}
__device__ __forceinline__ void gload_lds16(const unsigned short* g, unsigned short* l) {
  __builtin_amdgcn_global_load_lds(
      (const __attribute__((address_space(1))) unsigned int*)g,
      (__attribute__((address_space(3))) unsigned int*)l, 16, 0, 0);
}

// ---------------------------------------------------------------------------
// Pass 1: h = relu(conv1(pairfeat)+b) -> hbuf[b][i][j'][ch] bf16, + BN1
// partials. Weights as MFMA-A (D rows = ch, cols = j); 8-B stores per n.
// LDS cut to 37.9 KB (x1 half-tile, refilled at di=8; stats buffer unioned
// onto it) -> 4 blocks/CU with __launch_bounds__(256,4).
// grid (8 j-tiles, 32 i-tiles, 4 b), 256 thr.
// ---------------------------------------------------------------------------
__global__ __launch_bounds__(256, 4) void pass1(
    const float* __restrict__ x1, const float* __restrict__ x2,
    const float* __restrict__ c1w, const float* __restrict__ c1b,
    unsigned short* __restrict__ hbuf, float* __restrict__ partials)
{
  __shared__ unsigned short wgt[64][264];  // 33792 B, padded stride
  __shared__ float x1h[8][128];            // 4096 B half-tile; reused for stats

  const int tid = threadIdx.x;
  const int wv = tid >> 6, lane = tid & 63;
  const int lh = lane & 15, lg = lane >> 4;
  const int bx = blockIdx.x, by = blockIdx.y, bz = blockIdx.z;
  const int j0 = bx << 6, i0 = by << 4;

  { // stage x1 rows 0..7 (8 x 128 f32)
    int r = tid >> 5, c = (tid & 31) << 2;
    *(f32x4*)&x1h[r][c] = *(const f32x4*)(x1 + ((size_t)(bz * LL + i0 + r) * DD + c));
  }
  for (int idx = tid; idx < 64 * 256; idx += 256) {
    int h = idx >> 8;
    float v = (h < HH) ? c1w[idx] : 0.f;
    wgt[h][idx & 255] = f2bf(v);
  }
  __syncthreads();

  // weight A-frags: lane holds A[row=lh -> ch][k = kt*32+lg*8+e]
  // (compiler rematerializes these from LDS per use; kept as source-level loads)
  v8s bfr[4][8];
#pragma unroll
  for (int n = 0; n < 4; n++)
#pragma unroll
    for (int kt = 0; kt < 8; kt++)
      bfr[n][kt] = *(const v8s*)&wgt[n * 16 + lh][kt * 32 + lg * 8];

  // x2 row for this lane's j
  float x2v[4][8];
  {
    const int j = j0 + (wv << 4) + lh;
    const float* g = x2 + ((size_t)(bz * LL + j) * DD + (lg << 3));
#pragma unroll
    for (int kt = 0; kt < 4; kt++) {
      f32x4 a = *(const f32x4*)(g + kt * 32);
      f32x4 b = *(const f32x4*)(g + kt * 32 + 4);
#pragma unroll
      for (int e = 0; e < 4; e++) { x2v[kt][e] = a[e]; x2v[kt][4 + e] = b[e]; }
    }
  }
  float bias[4][4];
#pragma unroll
  for (int n = 0; n < 4; n++)
#pragma unroll
    for (int q = 0; q < 4; q++) {
      int h = n * 16 + (lg << 2) + q;
      bias[n][q] = (h < HH) ? c1b[h] : 0.f;
    }

  float ssum[4][4], ssq[4][4];
#pragma unroll
  for (int n = 0; n < 4; n++)
#pragma unroll
    for (int q = 0; q < 4; q++) { ssum[n][q] = 0.f; ssq[n][q] = 0.f; }

  unsigned short* hb = hbuf +
      ((size_t)(bz * LL + i0) * JW + 4 + j0 + (wv << 4) + lh) * 64 + (lg << 2);

  for (int di = 0; di < 16; ++di) {
    if (di == 8) { // refill half-tile with rows 8..15
      __syncthreads();
      int r = tid >> 5, c = (tid & 31) << 2;
      *(f32x4*)&x1h[r][c] =
          *(const f32x4*)(x1 + ((size_t)(bz * LL + i0 + 8 + r) * DD + c));
      __syncthreads();
    }
    f32x4 acc[4];
#pragma unroll
    for (int n = 0; n < 4; n++) acc[n] = f32x4{0.f, 0.f, 0.f, 0.f};
#pragma unroll
    for (int kt = 0; kt < 4; ++kt) {
      f32x4 p = *(const f32x4*)&x1h[di & 7][kt * 32 + (lg << 3)];
      f32x4 r = *(const f32x4*)&x1h[di & 7][kt * 32 + (lg << 3) + 4];
      float xv[8];
#pragma unroll
      for (int e = 0; e < 4; e++) { xv[e] = p[e]; xv[4 + e] = r[e]; }
      u32x4 ad, am;
#pragma unroll
      for (int m = 0; m < 4; m++) {
        ad[m] = cvtpkabs(xv[2*m] - x2v[kt][2*m], xv[2*m+1] - x2v[kt][2*m+1]);
        am[m] = cvtpk(xv[2*m] * x2v[kt][2*m], xv[2*m+1] * x2v[kt][2*m+1]);
      }
      v8s vad = __builtin_bit_cast(v8s, ad);
      v8s vam = __builtin_bit_cast(v8s, am);
#pragma unroll
      for (int n = 0; n < 4; n++)
        acc[n] = __builtin_amdgcn_mfma_f32_16x16x32_bf16(bfr[n][kt], vad, acc[n], 0, 0, 0);
#pragma unroll
      for (int n = 0; n < 4; n++)
        acc[n] = __builtin_amdgcn_mfma_f32_16x16x32_bf16(bfr[n][kt + 4], vam, acc[n], 0, 0, 0);
    }
    unsigned short* hp = hb + (size_t)di * (JW * 64);
#pragma unroll
    for (int n = 0; n < 4; ++n) {
      float vv[4];
#pragma unroll
      for (int q = 0; q < 4; ++q) {
        float v = acc[n][q] + bias[n][q];
        v = fmaxf(v, 0.f);
        ssum[n][q] += v; ssq[n][q] += v * v;
        vv[q] = v;
      }
      unsigned lo = cvtpk(vv[0], vv[1]), hi = cvtpk(vv[2], vv[3]);
      *(unsigned long long*)(hp + n * 16) = ((unsigned long long)hi << 32) | lo;
    }
  }

  // stats: reduce over j (lh lanes) -> stred[wave][h] (x1h storage reused)
  __syncthreads();
  float* stred = (float*)x1h;
#pragma unroll
  for (int n = 0; n < 4; ++n)
#pragma unroll
    for (int q = 0; q < 4; ++q) {
      float s = ssum[n][q], t = ssq[n][q];
#pragma unroll
      for (int m = 1; m < 16; m <<= 1) { s += __shfl_xor(s, m); t += __shfl_xor(t, m); }
      if (lh == 0) {
        stred[wv * 128 + n * 16 + (lg << 2) + q] = s;
        stred[wv * 128 + 64 + n * 16 + (lg << 2) + q] = t;
      }
    }
  __syncthreads();
  if (tid < 128) {
    int bid = (bz * gridDim.y + by) * gridDim.x + bx;
    partials[bid * 128 + tid] = stred[tid] + stred[128 + tid] + stred[256 + tid] + stred[384 + tid];
  }

  // zero the j' pads (bx 0 -> [0,4), bx 7 -> [516,520))
  if (bx == 0 || bx == 7) {
    const int jb = (bx == 0) ? 0 : 516;
#pragma unroll
    for (int k = 0; k < 2; ++k) {
      int unit = tid + (k << 8);
      int ii = unit >> 5;
      int rem = unit & 31;
      int jj = jb + (rem >> 3);
      int ch = (rem & 7) << 3;
      u32x4 z = {0u, 0u, 0u, 0u};
      *(u32x4*)&hbuf[((size_t)(bz * LL + i0 + ii) * JW + jj) * 64 + ch] = z;
    }
  }
}

// ---------------------------------------------------------------------------
// Pass 2a: reduce partials[1024][128] -> red1[64][128]
// ---------------------------------------------------------------------------
__global__ void pass2a(const float* __restrict__ partials, float* __restrict__ red1)
{
  __shared__ float acc2[2][128];
  const int tid = threadIdx.x, b = blockIdx.x;
  const int slot = tid & 127, half = tid >> 7;
  float s = 0.f;
#pragma unroll
  for (int k = 0; k < 8; k++)
    s += partials[(b * 16 + half * 8 + k) * 128 + slot];
  acc2[half][slot] = s;
  __syncthreads();
  if (tid < 128) red1[b * 128 + tid] = acc2[0][tid] + acc2[1][tid];
}

// ---------------------------------------------------------------------------
// Pass 2b (1 block): BN1 stats; wA[ky(16)][kx*64+ch] bf16 (BN1 scale folded);
// Tmap border constants.
// ---------------------------------------------------------------------------
__global__ void pass2b(const float* __restrict__ red1,
                       const float* __restrict__ c2w, const float* __restrict__ c2b,
                       const float* __restrict__ bn1g, const float* __restrict__ bn1b,
                       unsigned short* __restrict__ wA, float* __restrict__ tmap)
{
  __shared__ float acc2[2][128];
  __shared__ float sq[128];
  __shared__ float aa[64], cc[64];
  __shared__ float wlds[2450];
  __shared__ float tpart[49][5];
  const int tid = threadIdx.x;
  const int slot = tid & 127, half = tid >> 7;
  float s = 0.f;
#pragma unroll
  for (int k = 0; k < 32; k++) s += red1[(half * 32 + k) * 128 + slot];
  acc2[half][slot] = s;
  __syncthreads();
  if (tid < 128) sq[tid] = acc2[0][tid] + acc2[1][tid];
  for (int i = tid; i < 2450; i += 256) wlds[i] = c2w[i];
  __syncthreads();
  if (tid < HH) {
    float S = sq[tid], Q = sq[64 + tid];
    const float N = 4.0f * 512.f * 512.f;
    float m = S / N, v = fmaxf(Q / N - m * m, 0.f);
    float a = bn1g[tid] * rsqrtf(v + 1e-5f);
    aa[tid] = a;
    cc[tid] = bn1b[tid] - m * a;
  }
  __syncthreads();
  for (int idx = tid; idx < 16 * 448; idx += 256) {
    int ky = idx / 448, r = idx - ky * 448;
    int kx = r >> 6, ch = r & 63;
    float v = (ky < 7 && ch < HH) ? aa[ch] * wlds[ch * 49 + ky * 7 + kx] : 0.f;
    wA[idx] = f2bf(v);
  }
  if (tid < 245) {
    int c = tid / 5, g = tid - (tid / 5) * 5;
    int ci = c / 7, cj = c - (c / 7) * 7;
    int kylo = ci < 3 ? 3 - ci : 0, kyhi = ci > 3 ? 9 - ci : 6;
    int kxlo = cj < 3 ? 3 - cj : 0, kxhi = cj > 3 ? 9 - cj : 6;
    float t = 0.f;
    for (int h = g * 10; h < g * 10 + 10; h++) {
      float sm = 0.f;
      for (int ky = kylo; ky <= kyhi; ky++)
        for (int kx = kxlo; kx <= kxhi; kx++) sm += wlds[h * 49 + ky * 7 + kx];
      t += cc[h] * sm;
    }
    tpart[c][g] = t;
  }
  __syncthreads();
  if (tid < 49)
    tmap[tid] = c2b[0] + tpart[tid][0] + tpart[tid][1] + tpart[tid][2]
              + tpart[tid][3] + tpart[tid][4];
}

// ---------------------------------------------------------------------------
// Pass 3: 7x7 conv via MFMA ky-factorization on hbuf[b][i][j'][ch].
// Per row r: z[ky][j] (M=16 ky-pad, N=16 j/wave, K=448). Row staged with
// global_load_lds (src pre-XOR-swizzled, LDS linear). z distributed to owner
// lanes via 7 shfl; y kept in registers (ya[4], static ring via 8-unroll).
// grid (8, 32, 4), 256 thr, 1 barrier per row.
// ---------------------------------------------------------------------------
__global__ __launch_bounds__(256, 4) void pass3(
    const unsigned short* __restrict__ hbuf, const unsigned short* __restrict__ wA,
    const float* __restrict__ tmap, float* __restrict__ ybuf, float* __restrict__ part2)
{
  __shared__ unsigned short T[2][72 * 64];
  __shared__ float tm[49];
  __shared__ float rs[4], rq[4];

  const int tid = threadIdx.x;
  const int wv = tid >> 6, lane = tid & 63;
  const int lh = lane & 15, lg = lane >> 4;
  const int bx = blockIdx.x, by = blockIdx.y, bz = blockIdx.z;
  const int j0 = bx << 6, i0 = by << 4;

  v8s afr[14];
#pragma unroll
  for (int kt = 0; kt < 14; kt++)
    afr[kt] = *(const v8s*)&wA[lh * 448 + kt * 32 + (lg << 3)];

  if (tid < 49) tm[tid] = tmap[tid];

  const int jc = (wv << 4) + lh;
  float ya[4] = {0.f, 0.f, 0.f, 0.f};

  auto stage = [&](int buf, int row) {
    const unsigned short* rowp = hbuf + ((size_t)(bz * LL + row) * JW + j0) * 64;
#pragma unroll
    for (int cc2 = 0; cc2 < 2; ++cc2) {
      const int c = wv + (cc2 << 2);
      const int u = (c << 6) + lane;
      const int tj = u >> 3, oct = u & 7;
      gload_lds16(rowp + tj * 64 + ((oct ^ (tj & 7)) << 3), &T[buf][c << 9]);
    }
    if (wv == 0) {
      const int u = 512 + lane;
      const int tj = u >> 3, oct = u & 7;
      gload_lds16(rowp + tj * 64 + ((oct ^ (tj & 7)) << 3), &T[buf][8 << 9]);
    }
  };

  { const int r0 = i0 - 3; if (r0 >= 0) stage(0, r0); }
  __syncthreads();

  for (int rb = 0; rb < 24; rb += 8) {
#pragma unroll
    for (int u8 = 0; u8 < 8; ++u8) {
      const int rr = rb + u8;
      const int r = i0 - 3 + rr;
      const int cur = rr & 1;
      if (rr + 1 < 22) {
        const int rn = r + 1;
        if (rn >= 0 && rn < LL) stage(cur ^ 1, rn);
      }
      if (rr < 22 && r >= 0 && r < LL) {
        f32x4 a0 = {0.f, 0.f, 0.f, 0.f}, a1 = {0.f, 0.f, 0.f, 0.f};
#pragma unroll
        for (int kt = 0; kt < 14; ++kt) {
          const int kx = kt >> 1;
          const int t = jc + 1 + kx;
          const int sl = ((kt & 1) << 2) + lg;
          v8s b = *(const v8s*)&T[cur][(t << 6) + ((sl ^ (t & 7)) << 3)];
          if (kt & 1) a1 = __builtin_amdgcn_mfma_f32_16x16x32_bf16(afr[kt], b, a1, 0, 0, 0);
          else        a0 = __builtin_amdgcn_mfma_f32_16x16x32_bf16(afr[kt], b, a0, 0, 0, 0);
        }
        float zq[4];
#pragma unroll
        for (int q = 0; q < 4; ++q) zq[q] = a0[q] + a1[q];
#pragma unroll
        for (int ky = 0; ky < 7; ++ky) {
          float zz = __shfl(zq[ky & 3], ((ky >> 2) << 4) + lh, 64);
          const int idx = rr - ky;
          const bool ok = ((unsigned)idx < 16u) && ((idx >> 2) == lg);
          ya[(u8 - ky) & 3] += ok ? zz : 0.f;
        }
      }
      __syncthreads();
    }
  }

  float sa = 0.f, qa = 0.f;
  const int jj = j0 + jc;
  const int cj = jj < 3 ? jj : (jj > 508 ? jj - 505 : 3);
#pragma unroll
  for (int s = 0; s < 4; ++s) {
    const int i = i0 + (lg << 2) + s;
    const int ci = i < 3 ? i : (i > 508 ? i - 505 : 3);
    float v = ya[s] + tm[ci * 7 + cj];
    ybuf[(size_t)(bz * LL + i) * LL + jj] = v;
    sa += v; qa += v * v;
  }
#pragma unroll
  for (int m = 1; m < 64; m <<= 1) { sa += __shfl_xor(sa, m); qa += __shfl_xor(qa, m); }
  if (lane == 0) { rs[wv] = sa; rq[wv] = qa; }
  __syncthreads();
  if (tid == 0) {
    const int bid = (bz * gridDim.y + by) * gridDim.x + bx;
    part2[bid] = rs[0] + rs[1] + rs[2] + rs[3];
    part2[1024 + bid] = rq[0] + rq[1] + rq[2] + rq[3];
  }
}

// ---------------------------------------------------------------------------
// Pass 3b (1 block): finalize BN2 stats.
// ---------------------------------------------------------------------------
__global__ void pass3b(const float* __restrict__ part2, float* __restrict__ stats2)
{
  __shared__ float rs[4], rq[4];
  const int tid = threadIdx.x;
  float s = 0.f, q = 0.f;
  for (int i = tid; i < 1024; i += 256) { s += part2[i]; q += part2[1024 + i]; }
#pragma unroll
  for (int m = 1; m < 64; m <<= 1) { s += __shfl_xor(s, m); q += __shfl_xor(q, m); }
  const int wave = tid >> 6, lane = tid & 63;
  if (lane == 0) { rs[wave] = s; rq[wave] = q; }
  __syncthreads();
  if (tid == 0) {
    float S = rs[0] + rs[1] + rs[2] + rs[3];
    float Q = rq[0] + rq[1] + rq[2] + rq[3];
    const float N = 4.0f * 512.f * 512.f;
    float m2 = S / N, v2 = fmaxf(Q / N - m2 * m2, 0.f);
    stats2[0] = m2;
    stats2[1] = rsqrtf(v2 + 1e-5f);
  }
}

// ---------------------------------------------------------------------------
// Pass 4: BN2 + sigmoid.
// ---------------------------------------------------------------------------
__global__ void pass4(const float* __restrict__ y, const float* __restrict__ stats2,
                      const float* __restrict__ bn2g, const float* __restrict__ bn2b,
                      float* __restrict__ out)
{
  const int idx = blockIdx.x * 256 + threadIdx.x;
  const float m2 = stats2[0], inv = stats2[1];
  const float g = bn2g[0], b = bn2b[0];
  f32x4 v = ((const f32x4*)y)[idx];
  f32x4 r;
#pragma unroll
  for (int e = 0; e < 4; e++) {
    float xn = (v[e] - m2) * inv * g + b;
    r[e] = 1.f / (1.f + __expf(-xn));
  }
  ((f32x4*)out)[idx] = r;
}

extern "C" void kernel_launch(void* const* d_in, const int* in_sizes, int n_in,
                              void* d_out, int out_size, void* d_ws, size_t ws_size,
                              hipStream_t stream) {
  (void)in_sizes; (void)n_in; (void)out_size; (void)ws_size;
  const float* x1   = (const float*)d_in[0];
  const float* x2   = (const float*)d_in[1];
  const float* c1w  = (const float*)d_in[2];
  const float* c1b  = (const float*)d_in[3];
  const float* bn1g = (const float*)d_in[4];
  const float* bn1b = (const float*)d_in[5];
  const float* c2w  = (const float*)d_in[6];
  const float* c2b  = (const float*)d_in[7];
  const float* bn2g = (const float*)d_in[8];
  const float* bn2b = (const float*)d_in[9];

  char* ws = (char*)d_ws;
  float* partials       = (float*)(ws + 0);         // 1024*128*4 = 524288
  float* red1           = (float*)(ws + 524288);    // 64*128*4   = 32768
  float* part2          = (float*)(ws + 557056);    // 2048*4     = 8192
  unsigned short* wA    = (unsigned short*)(ws + 565248); // 16*448*2 = 14336
  float* tmap           = (float*)(ws + 579584);    // 49*4
  float* stats2         = (float*)(ws + 579840);    // 2*4
  float* ybuf           = (float*)(ws + 1048576);   // 4 MB
  unsigned short* hbuf  = (unsigned short*)(ws + 5242880); // 4*512*520*64*2 = 136.3 MB

  pass1<<<dim3(8, 32, 4), 256, 0, stream>>>(x1, x2, c1w, c1b, hbuf, partials);
  pass2a<<<64, 256, 0, stream>>>(partials, red1);
  pass2b<<<1, 256, 0, stream>>>(red1, c2w, c2b, bn1g, bn1b, wA, tmap);
  pass3<<<dim3(8, 32, 4), 256, 0, stream>>>(hbuf, wA, tmap, ybuf, part2);
  pass3b<<<1, 256, 0, stream>>>(part2, stats2);
  pass4<<<1024, 256, 0, stream>>>(ybuf, stats2, bn2g, bn2b, (float*)d_out);
}

// Round 5
// 148.773 us; speedup vs baseline: 2.7194x; 2.7194x over previous
//
#include <hip/hip_runtime.h>

#define LL 512
#define DD 128
#define HH 50
#define JW 520   // padded j' width (4 + 512 + 4)

typedef short v8s __attribute__((ext_vector_type(8)));
typedef float f32x4 __attribute__((ext_vector_type(4)));
typedef unsigned int u32x4 __attribute__((ext_vector_type(4)));

__device__ __forceinline__ unsigned cvtpk(float a, float b) {
  unsigned r;
  asm("v_cvt_pk_bf16_f32 %0, %1, %2" : "=v"(r) : "v"(a), "v"(b));
  return r;
}
__device__ __forceinline__ unsigned cvtpkabs(float a, float b) {
  unsigned r;
  asm("v_cvt_pk_bf16_f32 %0, abs(%1), abs(%2)" : "=v"(r) : "v"(a), "v"(b));
  return r;
}
__device__ __forceinline__ unsigned short f2bf(float f) {
  unsigned u = __builtin_bit_cast(unsigned, f);
  u = (u + 0x7fffu + ((u >> 16) & 1u)) >> 16;
  return (unsigned short)u;
}
__device__ __forceinline__ void gload_lds16(const unsigned short* g, unsigned short* l) {
  __builtin_amdgcn_global_load_lds(
      (const __attribute__((address_space(1))) unsigned int*)g,
      (__attribute__((address_space(3))) unsigned int*)l, 16, 0, 0);
}

// ---------------------------------------------------------------------------
// Pass 1: h = relu(conv1(pairfeat)+b) -> hbuf[b][i][j'][ch] bf16, + BN1
// partials. Weights as MFMA-A (D rows = ch, cols = j); 8-B stores per n.
// Weight fragments loaded via inline-asm ds_read_b128 ONCE (opaque to the
// rematerializer -> stay VGPR-resident; this was the R3 LDS-pipe bottleneck).
// __launch_bounds__(256,2): VGPR cap 256 (~220 needed). NEVER use min-waves
// >=3 here: R4 showed it clamps to 64 VGPR and spills (FETCH 958 MB).
// grid (8 j-tiles, 32 i-tiles, 4 b), 256 thr.
// ---------------------------------------------------------------------------
__global__ __launch_bounds__(256, 2) void pass1(
    const float* __restrict__ x1, const float* __restrict__ x2,
    const float* __restrict__ c1w, const float* __restrict__ c1b,
    unsigned short* __restrict__ hbuf, float* __restrict__ partials)
{
  __shared__ float x1s[16][128];
  __shared__ unsigned short wgt[64][264];
  __shared__ float stred[4][128];

  const int tid = threadIdx.x;
  const int wv = tid >> 6, lane = tid & 63;
  const int lh = lane & 15, lg = lane >> 4;
  const int bx = blockIdx.x, by = blockIdx.y, bz = blockIdx.z;
  const int j0 = bx << 6, i0 = by << 4;

  { // stage x1 tile (16 x 128 f32)
    int r = tid >> 4, c = (tid & 15) << 3;
    const float* g = x1 + ((size_t)(bz * LL + i0 + r) * DD + c);
    *(f32x4*)&x1s[r][c] = *(const f32x4*)g;
    *(f32x4*)&x1s[r][c + 4] = *(const f32x4*)(g + 4);
  }
  for (int idx = tid; idx < 64 * 256; idx += 256) {
    int h = idx >> 8;
    float v = (h < HH) ? c1w[idx] : 0.f;
    wgt[h][idx & 255] = f2bf(v);
  }
  __syncthreads();

  // weight A-frags: lane holds A[row=lh -> ch][k = kt*32+lg*8+e].
  // asm ds_read_b128 so the compiler CANNOT rematerialize from LDS per use.
  v8s bfr[4][8];
  {
    const unsigned wbase = (unsigned)(size_t)
        ((__attribute__((address_space(3))) char*)&wgt[0][0]);
#pragma unroll
    for (int n = 0; n < 4; n++)
#pragma unroll
      for (int kt = 0; kt < 8; kt++) {
        unsigned off = wbase + (unsigned)(((n * 16 + lh) * 264 + kt * 32 + lg * 8) << 1);
        asm volatile("ds_read_b128 %0, %1" : "=v"(bfr[n][kt]) : "v"(off));
      }
    asm volatile("s_waitcnt lgkmcnt(0)" ::: "memory");
    __builtin_amdgcn_sched_barrier(0);
  }

  // x2 row for this lane's j
  float x2v[4][8];
  {
    const int j = j0 + (wv << 4) + lh;
    const float* g = x2 + ((size_t)(bz * LL + j) * DD + (lg << 3));
#pragma unroll
    for (int kt = 0; kt < 4; kt++) {
      f32x4 a = *(const f32x4*)(g + kt * 32);
      f32x4 b = *(const f32x4*)(g + kt * 32 + 4);
#pragma unroll
      for (int e = 0; e < 4; e++) { x2v[kt][e] = a[e]; x2v[kt][4 + e] = b[e]; }
    }
  }
  float bias[4][4];
#pragma unroll
  for (int n = 0; n < 4; n++)
#pragma unroll
    for (int q = 0; q < 4; q++) {
      int h = n * 16 + (lg << 2) + q;
      bias[n][q] = (h < HH) ? c1b[h] : 0.f;
    }

  float ssum[4][4], ssq[4][4];
#pragma unroll
  for (int n = 0; n < 4; n++)
#pragma unroll
    for (int q = 0; q < 4; q++) { ssum[n][q] = 0.f; ssq[n][q] = 0.f; }

  unsigned short* hb = hbuf +
      ((size_t)(bz * LL + i0) * JW + 4 + j0 + (wv << 4) + lh) * 64 + (lg << 2);

  for (int di = 0; di < 16; ++di) {
    f32x4 acc[4];
#pragma unroll
    for (int n = 0; n < 4; n++) acc[n] = f32x4{0.f, 0.f, 0.f, 0.f};
#pragma unroll
    for (int kt = 0; kt < 4; ++kt) {
      f32x4 p = *(const f32x4*)&x1s[di][kt * 32 + (lg << 3)];
      f32x4 r = *(const f32x4*)&x1s[di][kt * 32 + (lg << 3) + 4];
      float xv[8];
#pragma unroll
      for (int e = 0; e < 4; e++) { xv[e] = p[e]; xv[4 + e] = r[e]; }
      u32x4 ad, am;
#pragma unroll
      for (int m = 0; m < 4; m++) {
        ad[m] = cvtpkabs(xv[2*m] - x2v[kt][2*m], xv[2*m+1] - x2v[kt][2*m+1]);
        am[m] = cvtpk(xv[2*m] * x2v[kt][2*m], xv[2*m+1] * x2v[kt][2*m+1]);
      }
      v8s vad = __builtin_bit_cast(v8s, ad);
      v8s vam = __builtin_bit_cast(v8s, am);
#pragma unroll
      for (int n = 0; n < 4; n++)
        acc[n] = __builtin_amdgcn_mfma_f32_16x16x32_bf16(bfr[n][kt], vad, acc[n], 0, 0, 0);
#pragma unroll
      for (int n = 0; n < 4; n++)
        acc[n] = __builtin_amdgcn_mfma_f32_16x16x32_bf16(bfr[n][kt + 4], vam, acc[n], 0, 0, 0);
    }
    unsigned short* hp = hb + (size_t)di * (JW * 64);
#pragma unroll
    for (int n = 0; n < 4; ++n) {
      float vv[4];
#pragma unroll
      for (int q = 0; q < 4; ++q) {
        float v = acc[n][q] + bias[n][q];
        v = fmaxf(v, 0.f);
        ssum[n][q] += v; ssq[n][q] += v * v;
        vv[q] = v;
      }
      unsigned lo = cvtpk(vv[0], vv[1]), hi = cvtpk(vv[2], vv[3]);
      *(unsigned long long*)(hp + n * 16) = ((unsigned long long)hi << 32) | lo;
    }
  }

  // stats: reduce over j (lh lanes) -> stred[wave][h]
#pragma unroll
  for (int n = 0; n < 4; ++n)
#pragma unroll
    for (int q = 0; q < 4; ++q) {
      float s = ssum[n][q], t = ssq[n][q];
#pragma unroll
      for (int m = 1; m < 16; m <<= 1) { s += __shfl_xor(s, m); t += __shfl_xor(t, m); }
      if (lh == 0) {
        stred[wv][n * 16 + (lg << 2) + q] = s;
        stred[wv][64 + n * 16 + (lg << 2) + q] = t;
      }
    }
  __syncthreads();
  if (tid < 128) {
    int bid = (bz * gridDim.y + by) * gridDim.x + bx;
    partials[bid * 128 + tid] = stred[0][tid] + stred[1][tid] + stred[2][tid] + stred[3][tid];
  }

  // zero the j' pads (bx 0 -> [0,4), bx 7 -> [516,520))
  if (bx == 0 || bx == 7) {
    const int jb = (bx == 0) ? 0 : 516;
#pragma unroll
    for (int k = 0; k < 2; ++k) {
      int unit = tid + (k << 8);
      int ii = unit >> 5;
      int rem = unit & 31;
      int jj = jb + (rem >> 3);
      int ch = (rem & 7) << 3;
      u32x4 z = {0u, 0u, 0u, 0u};
      *(u32x4*)&hbuf[((size_t)(bz * LL + i0 + ii) * JW + jj) * 64 + ch] = z;
    }
  }
}

// ---------------------------------------------------------------------------
// Pass 2a: reduce partials[1024][128] -> red1[64][128]
// ---------------------------------------------------------------------------
__global__ void pass2a(const float* __restrict__ partials, float* __restrict__ red1)
{
  __shared__ float acc2[2][128];
  const int tid = threadIdx.x, b = blockIdx.x;
  const int slot = tid & 127, half = tid >> 7;
  float s = 0.f;
#pragma unroll
  for (int k = 0; k < 8; k++)
    s += partials[(b * 16 + half * 8 + k) * 128 + slot];
  acc2[half][slot] = s;
  __syncthreads();
  if (tid < 128) red1[b * 128 + tid] = acc2[0][tid] + acc2[1][tid];
}

// ---------------------------------------------------------------------------
// Pass 2b (1 block): BN1 stats; wA[ky(16)][kx*64+ch] bf16 (BN1 scale folded);
// Tmap border constants.
// ---------------------------------------------------------------------------
__global__ void pass2b(const float* __restrict__ red1,
                       const float* __restrict__ c2w, const float* __restrict__ c2b,
                       const float* __restrict__ bn1g, const float* __restrict__ bn1b,
                       unsigned short* __restrict__ wA, float* __restrict__ tmap)
{
  __shared__ float acc2[2][128];
  __shared__ float sq[128];
  __shared__ float aa[64], cc[64];
  __shared__ float wlds[2450];
  __shared__ float tpart[49][5];
  const int tid = threadIdx.x;
  const int slot = tid & 127, half = tid >> 7;
  float s = 0.f;
#pragma unroll
  for (int k = 0; k < 32; k++) s += red1[(half * 32 + k) * 128 + slot];
  acc2[half][slot] = s;
  __syncthreads();
  if (tid < 128) sq[tid] = acc2[0][tid] + acc2[1][tid];
  for (int i = tid; i < 2450; i += 256) wlds[i] = c2w[i];
  __syncthreads();
  if (tid < HH) {
    float S = sq[tid], Q = sq[64 + tid];
    const float N = 4.0f * 512.f * 512.f;
    float m = S / N, v = fmaxf(Q / N - m * m, 0.f);
    float a = bn1g[tid] * rsqrtf(v + 1e-5f);
    aa[tid] = a;
    cc[tid] = bn1b[tid] - m * a;
  }
  __syncthreads();
  for (int idx = tid; idx < 16 * 448; idx += 256) {
    int ky = idx / 448, r = idx - ky * 448;
    int kx = r >> 6, ch = r & 63;
    float v = (ky < 7 && ch < HH) ? aa[ch] * wlds[ch * 49 + ky * 7 + kx] : 0.f;
    wA[idx] = f2bf(v);
  }
  if (tid < 245) {
    int c = tid / 5, g = tid - (tid / 5) * 5;
    int ci = c / 7, cj = c - (c / 7) * 7;
    int kylo = ci < 3 ? 3 - ci : 0, kyhi = ci > 3 ? 9 - ci : 6;
    int kxlo = cj < 3 ? 3 - cj : 0, kxhi = cj > 3 ? 9 - cj : 6;
    float t = 0.f;
    for (int h = g * 10; h < g * 10 + 10; h++) {
      float sm = 0.f;
      for (int ky = kylo; ky <= kyhi; ky++)
        for (int kx = kxlo; kx <= kxhi; kx++) sm += wlds[h * 49 + ky * 7 + kx];
      t += cc[h] * sm;
    }
    tpart[c][g] = t;
  }
  __syncthreads();
  if (tid < 49)
    tmap[tid] = c2b[0] + tpart[tid][0] + tpart[tid][1] + tpart[tid][2]
              + tpart[tid][3] + tpart[tid][4];
}

// ---------------------------------------------------------------------------
// Pass 3: 7x7 conv via MFMA ky-factorization on hbuf[b][i][j'][ch].
// Per row r: z[ky][j] (M=16 ky-pad, N=16 j/wave, K=448). Row staged with
// global_load_lds (src pre-XOR-swizzled, LDS linear). z distributed to owner
// lanes via 7 shfl; y kept in registers (ya[4], static ring via 8-unroll).
// grid (8, 32, 4), 256 thr, 1 barrier per row.
// ---------------------------------------------------------------------------
__global__ __launch_bounds__(256, 4) void pass3(
    const unsigned short* __restrict__ hbuf, const unsigned short* __restrict__ wA,
    const float* __restrict__ tmap, float* __restrict__ ybuf, float* __restrict__ part2)
{
  __shared__ unsigned short T[2][72 * 64];
  __shared__ float tm[49];
  __shared__ float rs[4], rq[4];

  const int tid = threadIdx.x;
  const int wv = tid >> 6, lane = tid & 63;
  const int lh = lane & 15, lg = lane >> 4;
  const int bx = blockIdx.x, by = blockIdx.y, bz = blockIdx.z;
  const int j0 = bx << 6, i0 = by << 4;

  v8s afr[14];
#pragma unroll
  for (int kt = 0; kt < 14; kt++)
    afr[kt] = *(const v8s*)&wA[lh * 448 + kt * 32 + (lg << 3)];

  if (tid < 49) tm[tid] = tmap[tid];

  const int jc = (wv << 4) + lh;
  float ya[4] = {0.f, 0.f, 0.f, 0.f};

  auto stage = [&](int buf, int row) {
    const unsigned short* rowp = hbuf + ((size_t)(bz * LL + row) * JW + j0) * 64;
#pragma unroll
    for (int cc2 = 0; cc2 < 2; ++cc2) {
      const int c = wv + (cc2 << 2);
      const int u = (c << 6) + lane;
      const int tj = u >> 3, oct = u & 7;
      gload_lds16(rowp + tj * 64 + ((oct ^ (tj & 7)) << 3), &T[buf][c << 9]);
    }
    if (wv == 0) {
      const int u = 512 + lane;
      const int tj = u >> 3, oct = u & 7;
      gload_lds16(rowp + tj * 64 + ((oct ^ (tj & 7)) << 3), &T[buf][8 << 9]);
    }
  };

  { const int r0 = i0 - 3; if (r0 >= 0) stage(0, r0); }
  __syncthreads();

  for (int rb = 0; rb < 24; rb += 8) {
#pragma unroll
    for (int u8 = 0; u8 < 8; ++u8) {
      const int rr = rb + u8;
      const int r = i0 - 3 + rr;
      const int cur = rr & 1;
      if (rr + 1 < 22) {
        const int rn = r + 1;
        if (rn >= 0 && rn < LL) stage(cur ^ 1, rn);
      }
      if (rr < 22 && r >= 0 && r < LL) {
        f32x4 a0 = {0.f, 0.f, 0.f, 0.f}, a1 = {0.f, 0.f, 0.f, 0.f};
#pragma unroll
        for (int kt = 0; kt < 14; ++kt) {
          const int kx = kt >> 1;
          const int t = jc + 1 + kx;
          const int sl = ((kt & 1) << 2) + lg;
          v8s b = *(const v8s*)&T[cur][(t << 6) + ((sl ^ (t & 7)) << 3)];
          if (kt & 1) a1 = __builtin_amdgcn_mfma_f32_16x16x32_bf16(afr[kt], b, a1, 0, 0, 0);
          else        a0 = __builtin_amdgcn_mfma_f32_16x16x32_bf16(afr[kt], b, a0, 0, 0, 0);
        }
        float zq[4];
#pragma unroll
        for (int q = 0; q < 4; ++q) zq[q] = a0[q] + a1[q];
#pragma unroll
        for (int ky = 0; ky < 7; ++ky) {
          float zz = __shfl(zq[ky & 3], ((ky >> 2) << 4) + lh, 64);
          const int idx = rr - ky;
          const bool ok = ((unsigned)idx < 16u) && ((idx >> 2) == lg);
          ya[(u8 - ky) & 3] += ok ? zz : 0.f;
        }
      }
      __syncthreads();
    }
  }

  float sa = 0.f, qa = 0.f;
  const int jj = j0 + jc;
  const int cj = jj < 3 ? jj : (jj > 508 ? jj - 505 : 3);
#pragma unroll
  for (int s = 0; s < 4; ++s) {
    const int i = i0 + (lg << 2) + s;
    const int ci = i < 3 ? i : (i > 508 ? i - 505 : 3);
    float v = ya[s] + tm[ci * 7 + cj];
    ybuf[(size_t)(bz * LL + i) * LL + jj] = v;
    sa += v; qa += v * v;
  }
#pragma unroll
  for (int m = 1; m < 64; m <<= 1) { sa += __shfl_xor(sa, m); qa += __shfl_xor(qa, m); }
  if (lane == 0) { rs[wv] = sa; rq[wv] = qa; }
  __syncthreads();
  if (tid == 0) {
    const int bid = (bz * gridDim.y + by) * gridDim.x + bx;
    part2[bid] = rs[0] + rs[1] + rs[2] + rs[3];
    part2[1024 + bid] = rq[0] + rq[1] + rq[2] + rq[3];
  }
}

// ---------------------------------------------------------------------------
// Pass 3b (1 block): finalize BN2 stats.
// ---------------------------------------------------------------------------
__global__ void pass3b(const float* __restrict__ part2, float* __restrict__ stats2)
{
  __shared__ float rs[4], rq[4];
  const int tid = threadIdx.x;
  float s = 0.f, q = 0.f;
  for (int i = tid; i < 1024; i += 256) { s += part2[i]; q += part2[1024 + i]; }
#pragma unroll
  for (int m = 1; m < 64; m <<= 1) { s += __shfl_xor(s, m); q += __shfl_xor(q, m); }
  const int wave = tid >> 6, lane = tid & 63;
  if (lane == 0) { rs[wave] = s; rq[wave] = q; }
  __syncthreads();
  if (tid == 0) {
    float S = rs[0] + rs[1] + rs[2] + rs[3];
    float Q = rq[0] + rq[1] + rq[2] + rq[3];
    const float N = 4.0f * 512.f * 512.f;
    float m2 = S / N, v2 = fmaxf(Q / N - m2 * m2, 0.f);
    stats2[0] = m2;
    stats2[1] = rsqrtf(v2 + 1e-5f);
  }
}

// ---------------------------------------------------------------------------
// Pass 4: BN2 + sigmoid.
// ---------------------------------------------------------------------------
__global__ void pass4(const float* __restrict__ y, const float* __restrict__ stats2,
                      const float* __restrict__ bn2g, const float* __restrict__ bn2b,
                      float* __restrict__ out)
{
  const int idx = blockIdx.x * 256 + threadIdx.x;
  const float m2 = stats2[0], inv = stats2[1];
  const float g = bn2g[0], b = bn2b[0];
  f32x4 v = ((const f32x4*)y)[idx];
  f32x4 r;
#pragma unroll
  for (int e = 0; e < 4; e++) {
    float xn = (v[e] - m2) * inv * g + b;
    r[e] = 1.f / (1.f + __expf(-xn));
  }
  ((f32x4*)out)[idx] = r;
}

extern "C" void kernel_launch(void* const* d_in, const int* in_sizes, int n_in,
                              void* d_out, int out_size, void* d_ws, size_t ws_size,
                              hipStream_t stream) {
  (void)in_sizes; (void)n_in; (void)out_size; (void)ws_size;
  const float* x1   = (const float*)d_in[0];
  const float* x2   = (const float*)d_in[1];
  const float* c1w  = (const float*)d_in[2];
  const float* c1b  = (const float*)d_in[3];
  const float* bn1g = (const float*)d_in[4];
  const float* bn1b = (const float*)d_in[5];
  const float* c2w  = (const float*)d_in[6];
  const float* c2b  = (const float*)d_in[7];
  const float* bn2g = (const float*)d_in[8];
  const float* bn2b = (const float*)d_in[9];

  char* ws = (char*)d_ws;
  float* partials       = (float*)(ws + 0);         // 1024*128*4 = 524288
  float* red1           = (float*)(ws + 524288);    // 64*128*4   = 32768
  float* part2          = (float*)(ws + 557056);    // 2048*4     = 8192
  unsigned short* wA    = (unsigned short*)(ws + 565248); // 16*448*2 = 14336
  float* tmap           = (float*)(ws + 579584);    // 49*4
  float* stats2         = (float*)(ws + 579840);    // 2*4
  float* ybuf           = (float*)(ws + 1048576);   // 4 MB
  unsigned short* hbuf  = (unsigned short*)(ws + 5242880); // 4*512*520*64*2 = 136.3 MB

  pass1<<<dim3(8, 32, 4), 256, 0, stream>>>(x1, x2, c1w, c1b, hbuf, partials);
  pass2a<<<64, 256, 0, stream>>>(partials, red1);
  pass2b<<<1, 256, 0, stream>>>(red1, c2w, c2b, bn1g, bn1b, wA, tmap);
  pass3<<<dim3(8, 32, 4), 256, 0, stream>>>(hbuf, wA, tmap, ybuf, part2);
  pass3b<<<1, 256, 0, stream>>>(part2, stats2);
  pass4<<<1024, 256, 0, stream>>>(ybuf, stats2, bn2g, bn2b, (float*)d_out);
}

// Round 6
// 120.863 us; speedup vs baseline: 3.3474x; 1.2309x over previous
//
#include <hip/hip_runtime.h>

#define LL 512
#define DD 128
#define HH 50
#define JW 520   // padded j' width (4 + 512 + 4)

typedef short v8s __attribute__((ext_vector_type(8)));
typedef float f32x4 __attribute__((ext_vector_type(4)));
typedef unsigned int u32x4 __attribute__((ext_vector_type(4)));

__device__ __forceinline__ unsigned cvtpk(float a, float b) {
  unsigned r;
  asm("v_cvt_pk_bf16_f32 %0, %1, %2" : "=v"(r) : "v"(a), "v"(b));
  return r;
}
__device__ __forceinline__ unsigned cvtpkabs(float a, float b) {
  unsigned r;
  asm("v_cvt_pk_bf16_f32 %0, abs(%1), abs(%2)" : "=v"(r) : "v"(a), "v"(b));
  return r;
}
__device__ __forceinline__ unsigned short f2bf(float f) {
  unsigned u = __builtin_bit_cast(unsigned, f);
  u = (u + 0x7fffu + ((u >> 16) & 1u)) >> 16;
  return (unsigned short)u;
}
__device__ __forceinline__ void gload_lds16(const unsigned short* g, unsigned short* l) {
  __builtin_amdgcn_global_load_lds(
      (const __attribute__((address_space(1))) unsigned int*)g,
      (__attribute__((address_space(3))) unsigned int*)l, 16, 0, 0);
}

// ---------------------------------------------------------------------------
// Pass 1: h = relu(conv1(pairfeat)+b) -> hbuf[b][i][j'][ch] bf16, + BN1
// partials. i-tile 32 (prologue amortized 2x vs R5), vectorized weight
// staging (16 independent f32x4 iters vs 64 dependent scalar), di-loop
// unroll 2 for cross-iteration ILP. NEVER min-waves >=3 (R4: spills).
// grid (8 j-tiles, 16 i-tiles, 4 b), 256 thr.
// ---------------------------------------------------------------------------
__global__ __launch_bounds__(256, 2) void pass1(
    const float* __restrict__ x1, const float* __restrict__ x2,
    const float* __restrict__ c1w, const float* __restrict__ c1b,
    unsigned short* __restrict__ hbuf, float* __restrict__ partials)
{
  __shared__ float x1s[32][128];           // 16 KB
  __shared__ unsigned short wgt[64][264];  // 33 KB
  __shared__ float stred[4][128];          // 2 KB

  const int tid = threadIdx.x;
  const int wv = tid >> 6, lane = tid & 63;
  const int lh = lane & 15, lg = lane >> 4;
  const int bx = blockIdx.x, by = blockIdx.y, bz = blockIdx.z;
  const int j0 = bx << 6, i0 = by << 5;

  { // stage x1 tile (32 x 128 f32): thread -> row tid>>3, cols (tid&7)*16..+16
    int r = tid >> 3, c = (tid & 7) << 4;
    const float* g = x1 + ((size_t)(bz * LL + i0 + r) * DD + c);
#pragma unroll
    for (int u = 0; u < 4; ++u)
      *(f32x4*)&x1s[r][c + 4 * u] = *(const f32x4*)(g + 4 * u);
  }
  { // stage weights: 16 independent f32x4 loads -> packed bf16 ds_write_b64
#pragma unroll
    for (int it = 0; it < 16; ++it) {
      int flat = (it * 256 + tid) << 2;     // f32 offset, multiple of 4
      int h = flat >> 8, col = flat & 255;
      f32x4 v = (h < HH) ? *(const f32x4*)(c1w + flat) : f32x4{0.f, 0.f, 0.f, 0.f};
      unsigned lo = cvtpk(v[0], v[1]), hi = cvtpk(v[2], v[3]);
      *(unsigned long long*)&wgt[h][col] = ((unsigned long long)hi << 32) | lo;
    }
  }
  __syncthreads();

  // weight A-frags: lane holds A[row=lh -> ch][k = kt*32+lg*8+e], pinned once
  v8s bfr[4][8];
  {
    const unsigned wbase = (unsigned)(size_t)
        ((__attribute__((address_space(3))) char*)&wgt[0][0]);
#pragma unroll
    for (int n = 0; n < 4; n++)
#pragma unroll
      for (int kt = 0; kt < 8; kt++) {
        unsigned off = wbase + (unsigned)(((n * 16 + lh) * 264 + kt * 32 + lg * 8) << 1);
        asm volatile("ds_read_b128 %0, %1" : "=v"(bfr[n][kt]) : "v"(off));
      }
    asm volatile("s_waitcnt lgkmcnt(0)" ::: "memory");
    __builtin_amdgcn_sched_barrier(0);
  }

  // x2 row for this lane's j
  float x2v[4][8];
  {
    const int j = j0 + (wv << 4) + lh;
    const float* g = x2 + ((size_t)(bz * LL + j) * DD + (lg << 3));
#pragma unroll
    for (int kt = 0; kt < 4; kt++) {
      f32x4 a = *(const f32x4*)(g + kt * 32);
      f32x4 b = *(const f32x4*)(g + kt * 32 + 4);
#pragma unroll
      for (int e = 0; e < 4; e++) { x2v[kt][e] = a[e]; x2v[kt][4 + e] = b[e]; }
    }
  }
  float bias[4][4];
#pragma unroll
  for (int n = 0; n < 4; n++)
#pragma unroll
    for (int q = 0; q < 4; q++) {
      int h = n * 16 + (lg << 2) + q;
      bias[n][q] = (h < HH) ? c1b[h] : 0.f;
    }

  float ssum[4][4], ssq[4][4];
#pragma unroll
  for (int n = 0; n < 4; n++)
#pragma unroll
    for (int q = 0; q < 4; q++) { ssum[n][q] = 0.f; ssq[n][q] = 0.f; }

  unsigned short* hb = hbuf +
      ((size_t)(bz * LL + i0) * JW + 4 + j0 + (wv << 4) + lh) * 64 + (lg << 2);

#pragma unroll 2
  for (int di = 0; di < 32; ++di) {
    f32x4 acc[4];
#pragma unroll
    for (int n = 0; n < 4; n++) acc[n] = f32x4{0.f, 0.f, 0.f, 0.f};
#pragma unroll
    for (int kt = 0; kt < 4; ++kt) {
      f32x4 p = *(const f32x4*)&x1s[di][kt * 32 + (lg << 3)];
      f32x4 r = *(const f32x4*)&x1s[di][kt * 32 + (lg << 3) + 4];
      float xv[8];
#pragma unroll
      for (int e = 0; e < 4; e++) { xv[e] = p[e]; xv[4 + e] = r[e]; }
      u32x4 ad, am;
#pragma unroll
      for (int m = 0; m < 4; m++) {
        ad[m] = cvtpkabs(xv[2*m] - x2v[kt][2*m], xv[2*m+1] - x2v[kt][2*m+1]);
        am[m] = cvtpk(xv[2*m] * x2v[kt][2*m], xv[2*m+1] * x2v[kt][2*m+1]);
      }
      v8s vad = __builtin_bit_cast(v8s, ad);
      v8s vam = __builtin_bit_cast(v8s, am);
#pragma unroll
      for (int n = 0; n < 4; n++)
        acc[n] = __builtin_amdgcn_mfma_f32_16x16x32_bf16(bfr[n][kt], vad, acc[n], 0, 0, 0);
#pragma unroll
      for (int n = 0; n < 4; n++)
        acc[n] = __builtin_amdgcn_mfma_f32_16x16x32_bf16(bfr[n][kt + 4], vam, acc[n], 0, 0, 0);
    }
    unsigned short* hp = hb + (size_t)di * (JW * 64);
#pragma unroll
    for (int n = 0; n < 4; ++n) {
      float vv[4];
#pragma unroll
      for (int q = 0; q < 4; ++q) {
        float v = acc[n][q] + bias[n][q];
        v = fmaxf(v, 0.f);
        ssum[n][q] += v; ssq[n][q] += v * v;
        vv[q] = v;
      }
      unsigned lo = cvtpk(vv[0], vv[1]), hi = cvtpk(vv[2], vv[3]);
      *(unsigned long long*)(hp + n * 16) = ((unsigned long long)hi << 32) | lo;
    }
  }

  // stats: reduce over j (lh lanes) -> stred[wave][h]
#pragma unroll
  for (int n = 0; n < 4; ++n)
#pragma unroll
    for (int q = 0; q < 4; ++q) {
      float s = ssum[n][q], t = ssq[n][q];
#pragma unroll
      for (int m = 1; m < 16; m <<= 1) { s += __shfl_xor(s, m); t += __shfl_xor(t, m); }
      if (lh == 0) {
        stred[wv][n * 16 + (lg << 2) + q] = s;
        stred[wv][64 + n * 16 + (lg << 2) + q] = t;
      }
    }
  __syncthreads();
  if (tid < 128) {
    int bid = (bz * gridDim.y + by) * gridDim.x + bx;
    partials[bid * 128 + tid] = stred[0][tid] + stred[1][tid] + stred[2][tid] + stred[3][tid];
  }

  // zero the j' pads (bx 0 -> [0,4), bx 7 -> [516,520)): 32 rows x 4 j x 64 ch
  if (bx == 0 || bx == 7) {
    const int jb = (bx == 0) ? 0 : 516;
#pragma unroll
    for (int k = 0; k < 4; ++k) {
      int unit = tid + (k << 8);
      int ii = unit >> 5;
      int rem = unit & 31;
      int jj = jb + (rem >> 3);
      int ch = (rem & 7) << 3;
      u32x4 z = {0u, 0u, 0u, 0u};
      *(u32x4*)&hbuf[((size_t)(bz * LL + i0 + ii) * JW + jj) * 64 + ch] = z;
    }
  }
}

// ---------------------------------------------------------------------------
// Pass 2a: reduce partials[512][128] -> red1[64][128]
// ---------------------------------------------------------------------------
__global__ void pass2a(const float* __restrict__ partials, float* __restrict__ red1)
{
  __shared__ float acc2[2][128];
  const int tid = threadIdx.x, b = blockIdx.x;
  const int slot = tid & 127, half = tid >> 7;
  float s = 0.f;
#pragma unroll
  for (int k = 0; k < 4; k++)
    s += partials[(b * 8 + half * 4 + k) * 128 + slot];
  acc2[half][slot] = s;
  __syncthreads();
  if (tid < 128) red1[b * 128 + tid] = acc2[0][tid] + acc2[1][tid];
}

// ---------------------------------------------------------------------------
// Pass 2b (1 block): BN1 stats; wA[ky(16)][kx*64+ch] bf16 (BN1 scale folded);
// Tmap border constants.
// ---------------------------------------------------------------------------
__global__ void pass2b(const float* __restrict__ red1,
                       const float* __restrict__ c2w, const float* __restrict__ c2b,
                       const float* __restrict__ bn1g, const float* __restrict__ bn1b,
                       unsigned short* __restrict__ wA, float* __restrict__ tmap)
{
  __shared__ float acc2[2][128];
  __shared__ float sq[128];
  __shared__ float aa[64], cc[64];
  __shared__ float wlds[2450];
  __shared__ float tpart[49][5];
  const int tid = threadIdx.x;
  const int slot = tid & 127, half = tid >> 7;
  float s = 0.f;
#pragma unroll
  for (int k = 0; k < 32; k++) s += red1[(half * 32 + k) * 128 + slot];
  acc2[half][slot] = s;
  __syncthreads();
  if (tid < 128) sq[tid] = acc2[0][tid] + acc2[1][tid];
  for (int i = tid; i < 2450; i += 256) wlds[i] = c2w[i];
  __syncthreads();
  if (tid < HH) {
    float S = sq[tid], Q = sq[64 + tid];
    const float N = 4.0f * 512.f * 512.f;
    float m = S / N, v = fmaxf(Q / N - m * m, 0.f);
    float a = bn1g[tid] * rsqrtf(v + 1e-5f);
    aa[tid] = a;
    cc[tid] = bn1b[tid] - m * a;
  }
  __syncthreads();
  for (int idx = tid; idx < 16 * 448; idx += 256) {
    int ky = idx / 448, r = idx - ky * 448;
    int kx = r >> 6, ch = r & 63;
    float v = (ky < 7 && ch < HH) ? aa[ch] * wlds[ch * 49 + ky * 7 + kx] : 0.f;
    wA[idx] = f2bf(v);
  }
  if (tid < 245) {
    int c = tid / 5, g = tid - (tid / 5) * 5;
    int ci = c / 7, cj = c - (c / 7) * 7;
    int kylo = ci < 3 ? 3 - ci : 0, kyhi = ci > 3 ? 9 - ci : 6;
    int kxlo = cj < 3 ? 3 - cj : 0, kxhi = cj > 3 ? 9 - cj : 6;
    float t = 0.f;
    for (int h = g * 10; h < g * 10 + 10; h++) {
      float sm = 0.f;
      for (int ky = kylo; ky <= kyhi; ky++)
        for (int kx = kxlo; kx <= kxhi; kx++) sm += wlds[h * 49 + ky * 7 + kx];
      t += cc[h] * sm;
    }
    tpart[c][g] = t;
  }
  __syncthreads();
  if (tid < 49)
    tmap[tid] = c2b[0] + tpart[tid][0] + tpart[tid][1] + tpart[tid][2]
              + tpart[tid][3] + tpart[tid][4];
}

// ---------------------------------------------------------------------------
// Pass 3: 7x7 conv via MFMA ky-factorization on hbuf[b][i][j'][ch].
// Per row r: z[ky][j] (M=16 ky-pad, N=16 j/wave, K=448). Row staged with
// global_load_lds (src pre-XOR-swizzled, LDS linear). z distributed to owner
// lanes via 7 shfl; y kept in registers (ya[4], static ring via 8-unroll).
// grid (8, 32, 4), 256 thr, 1 barrier per row.
// ---------------------------------------------------------------------------
__global__ __launch_bounds__(256, 4) void pass3(
    const unsigned short* __restrict__ hbuf, const unsigned short* __restrict__ wA,
    const float* __restrict__ tmap, float* __restrict__ ybuf, float* __restrict__ part2)
{
  __shared__ unsigned short T[2][72 * 64];
  __shared__ float tm[49];
  __shared__ float rs[4], rq[4];

  const int tid = threadIdx.x;
  const int wv = tid >> 6, lane = tid & 63;
  const int lh = lane & 15, lg = lane >> 4;
  const int bx = blockIdx.x, by = blockIdx.y, bz = blockIdx.z;
  const int j0 = bx << 6, i0 = by << 4;

  v8s afr[14];
#pragma unroll
  for (int kt = 0; kt < 14; kt++)
    afr[kt] = *(const v8s*)&wA[lh * 448 + kt * 32 + (lg << 3)];

  if (tid < 49) tm[tid] = tmap[tid];

  const int jc = (wv << 4) + lh;
  float ya[4] = {0.f, 0.f, 0.f, 0.f};

  auto stage = [&](int buf, int row) {
    const unsigned short* rowp = hbuf + ((size_t)(bz * LL + row) * JW + j0) * 64;
#pragma unroll
    for (int cc2 = 0; cc2 < 2; ++cc2) {
      const int c = wv + (cc2 << 2);
      const int u = (c << 6) + lane;
      const int tj = u >> 3, oct = u & 7;
      gload_lds16(rowp + tj * 64 + ((oct ^ (tj & 7)) << 3), &T[buf][c << 9]);
    }
    if (wv == 0) {
      const int u = 512 + lane;
      const int tj = u >> 3, oct = u & 7;
      gload_lds16(rowp + tj * 64 + ((oct ^ (tj & 7)) << 3), &T[buf][8 << 9]);
    }
  };

  { const int r0 = i0 - 3; if (r0 >= 0) stage(0, r0); }
  __syncthreads();

  for (int rb = 0; rb < 24; rb += 8) {
#pragma unroll
    for (int u8 = 0; u8 < 8; ++u8) {
      const int rr = rb + u8;
      const int r = i0 - 3 + rr;
      const int cur = rr & 1;
      if (rr + 1 < 22) {
        const int rn = r + 1;
        if (rn >= 0 && rn < LL) stage(cur ^ 1, rn);
      }
      if (rr < 22 && r >= 0 && r < LL) {
        f32x4 a0 = {0.f, 0.f, 0.f, 0.f}, a1 = {0.f, 0.f, 0.f, 0.f};
#pragma unroll
        for (int kt = 0; kt < 14; ++kt) {
          const int kx = kt >> 1;
          const int t = jc + 1 + kx;
          const int sl = ((kt & 1) << 2) + lg;
          v8s b = *(const v8s*)&T[cur][(t << 6) + ((sl ^ (t & 7)) << 3)];
          if (kt & 1) a1 = __builtin_amdgcn_mfma_f32_16x16x32_bf16(afr[kt], b, a1, 0, 0, 0);
          else        a0 = __builtin_amdgcn_mfma_f32_16x16x32_bf16(afr[kt], b, a0, 0, 0, 0);
        }
        float zq[4];
#pragma unroll
        for (int q = 0; q < 4; ++q) zq[q] = a0[q] + a1[q];
#pragma unroll
        for (int ky = 0; ky < 7; ++ky) {
          float zz = __shfl(zq[ky & 3], ((ky >> 2) << 4) + lh, 64);
          const int idx = rr - ky;
          const bool ok = ((unsigned)idx < 16u) && ((idx >> 2) == lg);
          ya[(u8 - ky) & 3] += ok ? zz : 0.f;
        }
      }
      __syncthreads();
    }
  }

  float sa = 0.f, qa = 0.f;
  const int jj = j0 + jc;
  const int cj = jj < 3 ? jj : (jj > 508 ? jj - 505 : 3);
#pragma unroll
  for (int s = 0; s < 4; ++s) {
    const int i = i0 + (lg << 2) + s;
    const int ci = i < 3 ? i : (i > 508 ? i - 505 : 3);
    float v = ya[s] + tm[ci * 7 + cj];
    ybuf[(size_t)(bz * LL + i) * LL + jj] = v;
    sa += v; qa += v * v;
  }
#pragma unroll
  for (int m = 1; m < 64; m <<= 1) { sa += __shfl_xor(sa, m); qa += __shfl_xor(qa, m); }
  if (lane == 0) { rs[wv] = sa; rq[wv] = qa; }
  __syncthreads();
  if (tid == 0) {
    const int bid = (bz * gridDim.y + by) * gridDim.x + bx;
    part2[bid] = rs[0] + rs[1] + rs[2] + rs[3];
    part2[1024 + bid] = rq[0] + rq[1] + rq[2] + rq[3];
  }
}

// ---------------------------------------------------------------------------
// Pass 3b (1 block): finalize BN2 stats.
// ---------------------------------------------------------------------------
__global__ void pass3b(const float* __restrict__ part2, float* __restrict__ stats2)
{
  __shared__ float rs[4], rq[4];
  const int tid = threadIdx.x;
  float s = 0.f, q = 0.f;
  for (int i = tid; i < 1024; i += 256) { s += part2[i]; q += part2[1024 + i]; }
#pragma unroll
  for (int m = 1; m < 64; m <<= 1) { s += __shfl_xor(s, m); q += __shfl_xor(q, m); }
  const int wave = tid >> 6, lane = tid & 63;
  if (lane == 0) { rs[wave] = s; rq[wave] = q; }
  __syncthreads();
  if (tid == 0) {
    float S = rs[0] + rs[1] + rs[2] + rs[3];
    float Q = rq[0] + rq[1] + rq[2] + rq[3];
    const float N = 4.0f * 512.f * 512.f;
    float m2 = S / N, v2 = fmaxf(Q / N - m2 * m2, 0.f);
    stats2[0] = m2;
    stats2[1] = rsqrtf(v2 + 1e-5f);
  }
}

// ---------------------------------------------------------------------------
// Pass 4: BN2 + sigmoid.
// ---------------------------------------------------------------------------
__global__ void pass4(const float* __restrict__ y, const float* __restrict__ stats2,
                      const float* __restrict__ bn2g, const float* __restrict__ bn2b,
                      float* __restrict__ out)
{
  const int idx = blockIdx.x * 256 + threadIdx.x;
  const float m2 = stats2[0], inv = stats2[1];
  const float g = bn2g[0], b = bn2b[0];
  f32x4 v = ((const f32x4*)y)[idx];
  f32x4 r;
#pragma unroll
  for (int e = 0; e < 4; e++) {
    float xn = (v[e] - m2) * inv * g + b;
    r[e] = 1.f / (1.f + __expf(-xn));
  }
  ((f32x4*)out)[idx] = r;
}

extern "C" void kernel_launch(void* const* d_in, const int* in_sizes, int n_in,
                              void* d_out, int out_size, void* d_ws, size_t ws_size,
                              hipStream_t stream) {
  (void)in_sizes; (void)n_in; (void)out_size; (void)ws_size;
  const float* x1   = (const float*)d_in[0];
  const float* x2   = (const float*)d_in[1];
  const float* c1w  = (const float*)d_in[2];
  const float* c1b  = (const float*)d_in[3];
  const float* bn1g = (const float*)d_in[4];
  const float* bn1b = (const float*)d_in[5];
  const float* c2w  = (const float*)d_in[6];
  const float* c2b  = (const float*)d_in[7];
  const float* bn2g = (const float*)d_in[8];
  const float* bn2b = (const float*)d_in[9];

  char* ws = (char*)d_ws;
  float* partials       = (float*)(ws + 0);         // 512*128*4 = 262144
  float* red1           = (float*)(ws + 524288);    // 64*128*4   = 32768
  float* part2          = (float*)(ws + 557056);    // 2048*4     = 8192
  unsigned short* wA    = (unsigned short*)(ws + 565248); // 16*448*2 = 14336
  float* tmap           = (float*)(ws + 579584);    // 49*4
  float* stats2         = (float*)(ws + 579840);    // 2*4
  float* ybuf           = (float*)(ws + 1048576);   // 4 MB
  unsigned short* hbuf  = (unsigned short*)(ws + 5242880); // 4*512*520*64*2 = 136.3 MB

  pass1<<<dim3(8, 16, 4), 256, 0, stream>>>(x1, x2, c1w, c1b, hbuf, partials);
  pass2a<<<64, 256, 0, stream>>>(partials, red1);
  pass2b<<<1, 256, 0, stream>>>(red1, c2w, c2b, bn1g, bn1b, wA, tmap);
  pass3<<<dim3(8, 32, 4), 256, 0, stream>>>(hbuf, wA, tmap, ybuf, part2);
  pass3b<<<1, 256, 0, stream>>>(part2, stats2);
  pass4<<<1024, 256, 0, stream>>>(ybuf, stats2, bn2g, bn2b, (float*)d_out);
}